// Round 2
// baseline (9508.954 us; speedup 1.0000x reference)
//
#include <hip/hip_runtime.h>
#include <hip/hip_bf16.h>

// ---------------------------------------------------------------------------
// DEQ layer (Anderson solver + spectral-norm MLP), MI355X round 1.
// Decisions:
//  - I/O dtype: float32 (per reference setup_inputs; round-1 NaN showed the
//    bf16 interpretation was wrong — misread f32-as-bf16 produces NaNs).
//  - Internal compute all f32: correctness baseline vs np ref.
//  - Power iteration: literal reference sequence, one block per weight.
//  - Anderson: wave-per-row, f64 5x5 solve in-registers, 7-slot ring.
//  - Final Anderson step (t=25) writes directly to d_out.
// ---------------------------------------------------------------------------

#define B_ROWS 2048
#define D_LAT  256
#define D_CTX  256
#define D_HID  1024
#define KCAT   (D_LAT + D_CTX)     // 512
#define SLOT   (B_ROWS * D_LAT)    // 524288 floats per X/F history slot
#define NRING  7

// ---------------- spectral norm (power iteration, literal ref sequence) ----
__device__ float block_sum_1024(float local, float* red) {
  for (int off = 32; off; off >>= 1) local += __shfl_down(local, off, 64);
  int wid = threadIdx.x >> 6, lane = threadIdx.x & 63;
  __syncthreads();                 // protect red[] from previous round's reads
  if (lane == 0) red[wid] = local;
  __syncthreads();
  if (threadIdx.x < 64) {
    float r = (threadIdx.x < 16) ? red[threadIdx.x] : 0.0f;
    for (int off = 8; off; off >>= 1) r += __shfl_down(r, off, 64);
    if (threadIdx.x == 0) red[0] = r;
  }
  __syncthreads();
  return red[0];
}

// blockIdx 0 -> W1 [1024x512], blockIdx 1 -> W2 [256x1024]. Writes 1/sigma.
__global__ __launch_bounds__(1024) void spectral_kernel(
    const float* __restrict__ W1, const float* __restrict__ W2,
    float* __restrict__ sig) {
  const float* W;
  int R, C;
  if (blockIdx.x == 0) { W = W1; R = D_HID; C = KCAT; }
  else                 { W = W2; R = D_LAT; C = D_HID; }

  __shared__ float u[1024];
  __shared__ float v[1024];
  __shared__ float red[16];
  int tid = threadIdx.x;

  // u = l2norm(ones(R))
  for (int i = tid; i < R; i += 1024) u[i] = 1.0f;
  __syncthreads();
  {
    float loc = 0.f;
    for (int i = tid; i < R; i += 1024) loc += u[i] * u[i];
    float nrm = sqrtf(block_sum_1024(loc, red));
    float inv = 1.0f / (nrm + 1e-12f);
    for (int i = tid; i < R; i += 1024) u[i] *= inv;
    __syncthreads();
  }

  // 20 body iterations (v then u), then one extra v (post-loop v = l2norm(W^T u))
  for (int iter = 0; iter <= 20; iter++) {
    // v = l2norm(W^T u)
    for (int j = tid; j < C; j += 1024) {
      float acc = 0.f;
      for (int i = 0; i < R; i++) acc += W[i * C + j] * u[i];
      v[j] = acc;
    }
    __syncthreads();
    float loc = 0.f;
    for (int j = tid; j < C; j += 1024) loc += v[j] * v[j];
    float nrm = sqrtf(block_sum_1024(loc, red));
    float inv = 1.0f / (nrm + 1e-12f);
    for (int j = tid; j < C; j += 1024) v[j] *= inv;
    __syncthreads();
    if (iter == 20) break;
    // u = l2norm(W v)
    for (int i = tid; i < R; i += 1024) {
      float acc = 0.f;
      for (int j = 0; j < C; j++) acc += W[i * C + j] * v[j];
      u[i] = acc;
    }
    __syncthreads();
    loc = 0.f;
    for (int i = tid; i < R; i += 1024) loc += u[i] * u[i];
    nrm = sqrtf(block_sum_1024(loc, red));
    inv = 1.0f / (nrm + 1e-12f);
    for (int i = tid; i < R; i += 1024) u[i] *= inv;
    __syncthreads();
  }

  // sigma = u @ (W v)
  float loc = 0.f;
  for (int i = tid; i < R; i += 1024) {
    float acc = 0.f;
    for (int j = 0; j < C; j++) acc += W[i * C + j] * v[j];
    loc += u[i] * acc;
  }
  float sigma = block_sum_1024(loc, red);
  if (tid == 0) sig[blockIdx.x] = 1.0f / sigma;
}

// ---------------- GEMM: C = tanh(inv_sigma * ([A0|A1] @ W^T) + bias) --------
// A = [A0 | A1] row-major concat along k (A0 width K0, A1 width K-K0).
// W row-major [N, K]. C row-major [B, N].
template <int BM, int BN, int BK, int TM, int TN>
__global__ __launch_bounds__((BM / TM) * (BN / TN)) void gemm_tanh_kernel(
    const float* __restrict__ A0, const float* __restrict__ A1, int K0, int K,
    const float* __restrict__ W, const float* __restrict__ bias,
    const float* __restrict__ invsig, float* __restrict__ C, int Brows, int N) {
  constexpr int THR = (BM / TM) * (BN / TN);
  __shared__ float As[BK][BM + 1];
  __shared__ float Ws[BK][BN + 1];
  const int bm = blockIdx.x * BM;
  const int bn = blockIdx.y * BN;
  const int tid = threadIdx.x;
  const int tx = tid % (BN / TN);
  const int ty = tid / (BN / TN);
  const int K1w = K - K0;
  float acc[TM][TN] = {};

  for (int k0 = 0; k0 < K; k0 += BK) {
    for (int idx = tid; idx < BM * BK; idx += THR) {
      int r = idx / BK, c = idx % BK;
      int kk = k0 + c;
      float val = (kk < K0) ? A0[(bm + r) * K0 + kk]
                            : A1[(bm + r) * K1w + (kk - K0)];
      As[c][r] = val;
    }
    for (int idx = tid; idx < BN * BK; idx += THR) {
      int n = idx / BK, c = idx % BK;
      Ws[c][n] = W[(bn + n) * K + k0 + c];
    }
    __syncthreads();
#pragma unroll
    for (int kk = 0; kk < BK; kk++) {
      float a[TM], w[TN];
#pragma unroll
      for (int i = 0; i < TM; i++) a[i] = As[kk][ty * TM + i];
#pragma unroll
      for (int j = 0; j < TN; j++) w[j] = Ws[kk][tx * TN + j];
#pragma unroll
      for (int i = 0; i < TM; i++)
#pragma unroll
        for (int j = 0; j < TN; j++) acc[i][j] += a[i] * w[j];
    }
    __syncthreads();
  }

  const float s = invsig[0];
#pragma unroll
  for (int i = 0; i < TM; i++) {
    int row = bm + ty * TM + i;
#pragma unroll
    for (int j = 0; j < TN; j++) {
      int col = bn + tx * TN + j;
      C[row * N + col] = tanhf(acc[i][j] * s + bias[col]);
    }
  }
}

// ---------------- Anderson step (wave per batch row) ------------------------
// Computes x_t = F[t-1] - dF @ alpha, writes into Xw (either the ring slot
// for position t, or d_out for the final step).
__global__ __launch_bounds__(256) void anderson_step_kernel(
    const float* __restrict__ Xh, const float* __restrict__ Fh,
    float* __restrict__ Xw, int t, int mk) {
  const int lane = threadIdx.x & 63;
  const int wid = threadIdx.x >> 6;
  const int b = blockIdx.x * 4 + wid;
  const int base = b * D_LAT + lane;

  float fa[4], xa[4], r[4], Fm1[4];
#pragma unroll
  for (int c = 0; c < 4; c++) {
    int sl = (t - 1) % NRING;
    fa[c] = Fh[sl * SLOT + base + 64 * c];
    xa[c] = Xh[sl * SLOT + base + 64 * c];
    r[c] = fa[c] - xa[c];
    Fm1[c] = fa[c];
  }

  float dF[5][4], dG[5][4];
  for (int i = 1; i <= mk; i++) {
    int sl = (t - 1 - i) % NRING;
#pragma unroll
    for (int c = 0; c < 4; c++) {
      float fb = Fh[sl * SLOT + base + 64 * c];
      float xb = Xh[sl * SLOT + base + 64 * c];
      dF[i - 1][c] = fa[c] - fb;
      float dx = xa[c] - xb;
      dG[i - 1][c] = dF[i - 1][c] - dx;
      fa[c] = fb;
      xa[c] = xb;
    }
  }

  // Partial sums for A (upper triangle) and Bv, then 64-lane butterfly.
  float vals[20];
  int nv = 0;
  for (int i = 0; i < mk; i++)
    for (int j = i; j < mk; j++) {
      float s = 0.f;
#pragma unroll
      for (int c = 0; c < 4; c++) s += dG[i][c] * dG[j][c];
      vals[nv++] = s;
    }
  for (int i = 0; i < mk; i++) {
    float s = 0.f;
#pragma unroll
    for (int c = 0; c < 4; c++) s += dG[i][c] * r[c];
    vals[nv++] = s;
  }
  for (int off = 1; off <= 32; off <<= 1)
    for (int v = 0; v < nv; v++) vals[v] += __shfl_xor(vals[v], off, 64);

  // Solve (A + 1e-4 I) alpha = Bv in f64 (SPD -> no pivoting needed).
  double A[5][5], bv[5], alpha[5];
  int p = 0;
  for (int i = 0; i < mk; i++)
    for (int j = i; j < mk; j++) {
      A[i][j] = (double)vals[p];
      A[j][i] = (double)vals[p];
      p++;
    }
  for (int i = 0; i < mk; i++) A[i][i] += (double)1e-4f;
  for (int i = 0; i < mk; i++) bv[i] = (double)vals[p++];

  for (int c = 0; c < mk; c++) {
    double inv = 1.0 / A[c][c];
    for (int rr = c + 1; rr < mk; rr++) {
      double fct = A[rr][c] * inv;
      for (int cc = c; cc < mk; cc++) A[rr][cc] -= fct * A[c][cc];
      bv[rr] -= fct * bv[c];
    }
  }
  for (int i = mk - 1; i >= 0; i--) {
    double s = bv[i];
    for (int j = i + 1; j < mk; j++) s -= A[i][j] * alpha[j];
    alpha[i] = s / A[i][i];
  }

#pragma unroll
  for (int c = 0; c < 4; c++) {
    float x = Fm1[c];
    for (int i = 0; i < mk; i++) x -= dF[i][c] * (float)alpha[i];
    Xw[base + 64 * c] = x;
  }
}

// ---------------- host orchestration ---------------------------------------
static void eval_f(const float* z, float* Fout, float* hbuf, const float* ctx,
                   const float* W1, const float* b1, const float* W2,
                   const float* b2, const float* sig, hipStream_t stream) {
  gemm_tanh_kernel<128, 64, 16, 8, 4>
      <<<dim3(B_ROWS / 128, D_HID / 64), 256, 0, stream>>>(
          z, ctx, D_LAT, KCAT, W1, b1, sig + 0, hbuf, B_ROWS, D_HID);
  gemm_tanh_kernel<64, 64, 16, 4, 4>
      <<<dim3(B_ROWS / 64, D_LAT / 64), 256, 0, stream>>>(
          hbuf, nullptr, D_HID, D_HID, W2, b2, sig + 1, Fout, B_ROWS, D_LAT);
}

extern "C" void kernel_launch(void* const* d_in, const int* in_sizes, int n_in,
                              void* d_out, int out_size, void* d_ws,
                              size_t ws_size, hipStream_t stream) {
  const float* ctx = (const float*)d_in[0];
  const float* W1 = (const float*)d_in[1];
  const float* b1 = (const float*)d_in[2];
  const float* W2 = (const float*)d_in[3];
  const float* b2 = (const float*)d_in[4];
  float* out = (float*)d_out;

  float* ws = (float*)d_ws;
  float* sig = ws;                     // [2] (padded to 16)
  float* hbuf = ws + 16;               // 2048*1024
  float* Xh = hbuf + B_ROWS * D_HID;   // 7 * SLOT
  float* Fh = Xh + NRING * SLOT;       // 7 * SLOT
  // total: 16 + 2097152 + 2*3670016 floats ~= 37.7 MB

  // Spectral norms (both weights concurrently, literal ref power iteration).
  spectral_kernel<<<2, 1024, 0, stream>>>(W1, W2, sig);

  // x0 = 0 at X position 0 (slot 0).
  hipMemsetAsync(Xh, 0, SLOT * sizeof(float), stream);

  // F[0] = f(x0)
  eval_f(Xh, Fh, hbuf, ctx, W1, b1, W2, b2, sig, stream);
  // X[1] = F[0]; F[1] = f(X[1])
  hipMemcpyAsync(Xh + 1 * SLOT, Fh, SLOT * sizeof(float),
                 hipMemcpyDeviceToDevice, stream);
  eval_f(Xh + 1 * SLOT, Fh + 1 * SLOT, hbuf, ctx, W1, b1, W2, b2, sig, stream);
  // X[2] = F[0]; F[2] = F[1]  (reference's duplicated warm-up)
  hipMemcpyAsync(Xh + 2 * SLOT, Fh, SLOT * sizeof(float),
                 hipMemcpyDeviceToDevice, stream);
  hipMemcpyAsync(Fh + 2 * SLOT, Fh + 1 * SLOT, SLOT * sizeof(float),
                 hipMemcpyDeviceToDevice, stream);

  // Anderson loop: positions t = 3..25 (k = 2..24). F at t=25 is unused.
  for (int t = 3; t <= 25; t++) {
    int mk = (t - 1 < 5) ? (t - 1) : 5;
    float* Xw = (t == 25) ? out : (Xh + (t % NRING) * SLOT);
    anderson_step_kernel<<<B_ROWS / 4, 256, 0, stream>>>(Xh, Fh, Xw, t, mk);
    if (t < 25) {
      eval_f(Xh + (t % NRING) * SLOT, Fh + (t % NRING) * SLOT, hbuf, ctx, W1,
             b1, W2, b2, sig, stream);
    }
  }
}

// Round 3
// 2516.078 us; speedup vs baseline: 3.7793x; 3.7793x over previous
//
#include <hip/hip_runtime.h>
#include <hip/hip_bf16.h>

// ---------------------------------------------------------------------------
// DEQ layer, MI355X round 2.
//  - Spectral norm: l2norm folding (direction-invariant) -> 20 unnormalized
//    G=W W^T iterations as whole-GPU matvec pairs; sigma = ||W^T u||/||u||.
//  - GEMMs: bf16 MFMA 16x16x32 (no f32 MFMA on CDNA4), f32 accumulate,
//    global_load_lds width=16 with XOR-octet swizzle (2-way bank = free),
//    sigma folded into bf16 weights before rounding, fused bias+tanh.
//  - Anderson: unchanged from round 1 (verified), plus fused bf16 z write.
// ---------------------------------------------------------------------------

#define B_ROWS 2048
#define D_LAT  256
#define D_CTX  256
#define D_HID  1024
#define KCAT   512
#define SLOT   (B_ROWS * D_LAT)
#define NRING  7

typedef __bf16 bf16x8 __attribute__((ext_vector_type(8)));
typedef float f32x4 __attribute__((ext_vector_type(4)));
typedef unsigned short u16;

// ---------------- init: zc = [bf16(0) | bf16(ctx)], u1=u2=1 ----------------
__global__ void init_kernel(const float* __restrict__ ctx,
                            __hip_bfloat16* __restrict__ zc,
                            float* __restrict__ u1, float* __restrict__ u2) {
  int i = blockIdx.x * 256 + threadIdx.x;
  if (i < B_ROWS * KCAT) {
    int b = i >> 9, c = i & 511;
    float v = (c < 256) ? 0.0f : ctx[b * 256 + (c - 256)];
    zc[i] = __float2bfloat16(v);
  }
  if (i < D_HID) u1[i] = 1.0f;
  if (i < D_LAT) u2[i] = 1.0f;
}

// ---------------- spectral: v = scale * W^T u (both weights) ---------------
// blocks 0..7 -> W1 (512 cols), 8..23 -> W2 (1024 cols). 64 cols per block.
__global__ __launch_bounds__(256) void s1_kernel(
    const float* __restrict__ W1, const float* __restrict__ W2,
    const float* __restrict__ u1, const float* __restrict__ u2,
    float* __restrict__ v1, float* __restrict__ v2, float scale) {
  const float* W; const float* u; float* v; int R, C, j0;
  int b = blockIdx.x;
  if (b < 8) { W = W1; u = u1; v = v1; R = D_HID; C = KCAT; j0 = b * 64; }
  else       { W = W2; u = u2; v = v2; R = D_LAT; C = D_HID; j0 = (b - 8) * 64; }
  int lane = threadIdx.x & 63, rg = threadIdx.x >> 6;
  float acc = 0.f;
  for (int i = rg; i < R; i += 4) acc += W[i * C + j0 + lane] * u[i];
  __shared__ float red[4][64];
  red[rg][lane] = acc;
  __syncthreads();
  if (threadIdx.x < 64) {
    int j = threadIdx.x;
    v[j0 + j] = scale * (red[0][j] + red[1][j] + red[2][j] + red[3][j]);
  }
}

// ---------------- spectral: u = 0.5 * W v (wave per row, both weights) -----
__global__ __launch_bounds__(256) void s2_kernel(
    const float* __restrict__ W1, const float* __restrict__ W2,
    const float* __restrict__ v1, const float* __restrict__ v2,
    float* __restrict__ u1, float* __restrict__ u2) {
  int row = blockIdx.x * 4 + (threadIdx.x >> 6);
  int lane = threadIdx.x & 63;
  const float* W; const float* v; float* u; int C, r;
  if (row < D_HID) { W = W1; v = v1; u = u1; C = KCAT; r = row; }
  else             { W = W2; v = v2; u = u2; C = D_HID; r = row - D_HID; }
  float acc = 0.f;
  for (int c = lane; c < C; c += 64) acc += W[r * C + c] * v[c];
  for (int off = 32; off; off >>= 1) acc += __shfl_down(acc, off, 64);
  if (lane == 0) u[r] = 0.5f * acc;
}

// ---------------- sigma: invsig = ||u|| / ||v_raw|| ------------------------
__global__ __launch_bounds__(256) void sigma_kernel(
    const float* __restrict__ u1, const float* __restrict__ u2,
    const float* __restrict__ v1, const float* __restrict__ v2,
    float* __restrict__ sig) {
  float s[4] = {0.f, 0.f, 0.f, 0.f};
  for (int i = threadIdx.x; i < D_HID; i += 256) s[0] += u1[i] * u1[i];
  for (int i = threadIdx.x; i < KCAT; i += 256) s[1] += v1[i] * v1[i];
  for (int i = threadIdx.x; i < D_LAT; i += 256) s[2] += u2[i] * u2[i];
  for (int i = threadIdx.x; i < D_HID; i += 256) s[3] += v2[i] * v2[i];
  __shared__ float red[4][4];
  int lane = threadIdx.x & 63, w = threadIdx.x >> 6;
  for (int k = 0; k < 4; k++) {
    float a = s[k];
    for (int off = 32; off; off >>= 1) a += __shfl_down(a, off, 64);
    if (lane == 0) red[k][w] = a;
  }
  __syncthreads();
  if (threadIdx.x == 0) {
    float su1 = 0, sv1 = 0, su2 = 0, sv2 = 0;
    for (int w2 = 0; w2 < 4; w2++) {
      su1 += red[0][w2]; sv1 += red[1][w2];
      su2 += red[2][w2]; sv2 += red[3][w2];
    }
    sig[0] = sqrtf(su1 / sv1);   // 1/sigma1 = ||u1|| / ||W1^T u1||
    sig[1] = sqrtf(su2 / sv2);
  }
}

// ---------------- fold sigma into bf16 weights -----------------------------
__global__ void wfold_kernel(const float* __restrict__ W1,
                             const float* __restrict__ W2,
                             const float* __restrict__ sig,
                             __hip_bfloat16* __restrict__ W1b,
                             __hip_bfloat16* __restrict__ W2b) {
  int i = blockIdx.x * 256 + threadIdx.x;
  if (i < D_HID * KCAT) W1b[i] = __float2bfloat16(W1[i] * sig[0]);
  int j = i - D_HID * KCAT;
  if (j >= 0 && j < D_LAT * D_HID) W2b[j] = __float2bfloat16(W2[j] * sig[1]);
}

// ---------------- cast F0 into zc left half --------------------------------
__global__ void zcast_kernel(const float* __restrict__ z,
                             __hip_bfloat16* __restrict__ zc) {
  int i = blockIdx.x * 256 + threadIdx.x;   // over 2048*256
  int b = i >> 8, c = i & 255;
  zc[b * KCAT + c] = __float2bfloat16(z[i]);
}

// ---------------- bf16 MFMA GEMM: C = tanh(A @ W^T + bias) -----------------
// A [M,K] bf16 row-major, W [N,K] bf16 row-major (sigma pre-folded).
// 2x2 waves per block; mfma_f32_16x16x32_bf16; BK=64; XOR-octet LDS swizzle.
template <int BM, int BN, bool OUT_BF16>
__global__ __launch_bounds__(256) void gemm_mfma(
    const __hip_bfloat16* __restrict__ A, const __hip_bfloat16* __restrict__ W,
    int K, const float* __restrict__ bias, float* __restrict__ Cf,
    __hip_bfloat16* __restrict__ Cb, int N) {
  __shared__ __align__(16) u16 lds[(BM + BN) * 64];
  u16* As = lds;
  u16* Ws = lds + BM * 64;
  const int tid = threadIdx.x;
  const int lane = tid & 63;
  const int wid = tid >> 6;
  const int wy = wid >> 1, wx = wid & 1;
  constexpr int WM = BM / 2, WN = BN / 2;
  constexpr int MB = WM / 16, NB = WN / 16;
  const int bm = blockIdx.x * BM;
  const int bn = blockIdx.y * BN;
  const int rlo = lane & 15, quad = lane >> 4;

  f32x4 acc[MB][NB] = {};

  for (int k0 = 0; k0 < K; k0 += 64) {
    // stage A-tile: chunk c (16B) at LDS pos c holds global octet (c&7)^(r&7)
    for (int c = tid; c < BM * 8; c += 256) {
      int r = c >> 3, o = (c & 7) ^ (r & 7);
      __builtin_amdgcn_global_load_lds(
          (const __attribute__((address_space(1))) void*)(A + (size_t)(bm + r) * K + k0 + o * 8),
          (__attribute__((address_space(3))) void*)(As + c * 8), 16, 0, 0);
    }
    for (int c = tid; c < BN * 8; c += 256) {
      int r = c >> 3, o = (c & 7) ^ (r & 7);
      __builtin_amdgcn_global_load_lds(
          (const __attribute__((address_space(1))) void*)(W + (size_t)(bn + r) * K + k0 + o * 8),
          (__attribute__((address_space(3))) void*)(Ws + c * 8), 16, 0, 0);
    }
    __syncthreads();
#pragma unroll
    for (int kk = 0; kk < 2; kk++) {
      bf16x8 af[MB], bfr[NB];
#pragma unroll
      for (int mb = 0; mb < MB; mb++) {
        int r = wy * WM + mb * 16 + rlo;
        int o = (kk * 4 + quad) ^ (r & 7);
        af[mb] = *(const bf16x8*)(As + (r * 8 + o) * 8);
      }
#pragma unroll
      for (int nb = 0; nb < NB; nb++) {
        int r = wx * WN + nb * 16 + rlo;
        int o = (kk * 4 + quad) ^ (r & 7);
        bfr[nb] = *(const bf16x8*)(Ws + (r * 8 + o) * 8);
      }
#pragma unroll
      for (int mb = 0; mb < MB; mb++)
#pragma unroll
        for (int nb = 0; nb < NB; nb++)
          acc[mb][nb] = __builtin_amdgcn_mfma_f32_16x16x32_bf16(
              af[mb], bfr[nb], acc[mb][nb], 0, 0, 0);
    }
    __syncthreads();
  }

  // epilogue: D col = lane&15 (n), row = quad*4+reg (m)
#pragma unroll
  for (int mb = 0; mb < MB; mb++) {
#pragma unroll
    for (int nb = 0; nb < NB; nb++) {
      int n = bn + wx * WN + nb * 16 + rlo;
      float bv = bias[n];
#pragma unroll
      for (int rg = 0; rg < 4; rg++) {
        int m = bm + wy * WM + mb * 16 + quad * 4 + rg;
        float val = tanhf(acc[mb][nb][rg] + bv);
        if constexpr (OUT_BF16) {
          Cb[(size_t)m * N + n] = __float2bfloat16(val);
        } else {
          Cf[(size_t)m * N + n] = val;
        }
      }
    }
  }
}

// ---------------- Anderson step (wave per batch row) ------------------------
__global__ __launch_bounds__(256) void anderson_step_kernel(
    const float* __restrict__ Xh, const float* __restrict__ Fh,
    float* __restrict__ Xw, __hip_bfloat16* __restrict__ zc, int t, int mk) {
  const int lane = threadIdx.x & 63;
  const int wid = threadIdx.x >> 6;
  const int b = blockIdx.x * 4 + wid;
  const int base = b * D_LAT + lane;

  float fa[4], xa[4], r[4], Fm1[4];
#pragma unroll
  for (int c = 0; c < 4; c++) {
    int sl = (t - 1) % NRING;
    fa[c] = Fh[sl * SLOT + base + 64 * c];
    xa[c] = Xh[sl * SLOT + base + 64 * c];
    r[c] = fa[c] - xa[c];
    Fm1[c] = fa[c];
  }

  float dF[5][4], dG[5][4];
  for (int i = 1; i <= mk; i++) {
    int sl = (t - 1 - i) % NRING;
#pragma unroll
    for (int c = 0; c < 4; c++) {
      float fb = Fh[sl * SLOT + base + 64 * c];
      float xb = Xh[sl * SLOT + base + 64 * c];
      dF[i - 1][c] = fa[c] - fb;
      float dx = xa[c] - xb;
      dG[i - 1][c] = dF[i - 1][c] - dx;
      fa[c] = fb;
      xa[c] = xb;
    }
  }

  float vals[20];
  int nv = 0;
  for (int i = 0; i < mk; i++)
    for (int j = i; j < mk; j++) {
      float s = 0.f;
#pragma unroll
      for (int c = 0; c < 4; c++) s += dG[i][c] * dG[j][c];
      vals[nv++] = s;
    }
  for (int i = 0; i < mk; i++) {
    float s = 0.f;
#pragma unroll
    for (int c = 0; c < 4; c++) s += dG[i][c] * r[c];
    vals[nv++] = s;
  }
  for (int off = 1; off <= 32; off <<= 1)
    for (int v = 0; v < nv; v++) vals[v] += __shfl_xor(vals[v], off, 64);

  double A[5][5], bv[5], alpha[5];
  int p = 0;
  for (int i = 0; i < mk; i++)
    for (int j = i; j < mk; j++) {
      A[i][j] = (double)vals[p];
      A[j][i] = (double)vals[p];
      p++;
    }
  for (int i = 0; i < mk; i++) A[i][i] += (double)1e-4f;
  for (int i = 0; i < mk; i++) bv[i] = (double)vals[p++];

  for (int c = 0; c < mk; c++) {
    double inv = 1.0 / A[c][c];
    for (int rr = c + 1; rr < mk; rr++) {
      double fct = A[rr][c] * inv;
      for (int cc = c; cc < mk; cc++) A[rr][cc] -= fct * A[c][cc];
      bv[rr] -= fct * bv[c];
    }
  }
  for (int i = mk - 1; i >= 0; i--) {
    double s = bv[i];
    for (int j = i + 1; j < mk; j++) s -= A[i][j] * alpha[j];
    alpha[i] = s / A[i][i];
  }

#pragma unroll
  for (int c = 0; c < 4; c++) {
    float x = Fm1[c];
    for (int i = 0; i < mk; i++) x -= dF[i][c] * (float)alpha[i];
    Xw[base + 64 * c] = x;
    if (zc != nullptr) zc[b * KCAT + lane + 64 * c] = __float2bfloat16(x);
  }
}

// ---------------- host orchestration ---------------------------------------
static void eval_f(const __hip_bfloat16* zc, const __hip_bfloat16* W1b,
                   const __hip_bfloat16* W2b, const float* b1, const float* b2,
                   __hip_bfloat16* hb, float* Fout, hipStream_t stream) {
  gemm_mfma<64, 128, true><<<dim3(B_ROWS / 64, D_HID / 128), 256, 0, stream>>>(
      zc, W1b, KCAT, b1, nullptr, hb, D_HID);
  gemm_mfma<64, 64, false><<<dim3(B_ROWS / 64, D_LAT / 64), 256, 0, stream>>>(
      hb, W2b, D_HID, b2, Fout, nullptr, D_LAT);
}

extern "C" void kernel_launch(void* const* d_in, const int* in_sizes, int n_in,
                              void* d_out, int out_size, void* d_ws,
                              size_t ws_size, hipStream_t stream) {
  const float* ctx = (const float*)d_in[0];
  const float* W1 = (const float*)d_in[1];
  const float* b1 = (const float*)d_in[2];
  const float* W2 = (const float*)d_in[3];
  const float* b2 = (const float*)d_in[4];
  float* out = (float*)d_out;

  float* ws = (float*)d_ws;
  float* sig = ws;                      // 16
  float* u1 = ws + 16;                  // 1024
  float* u2 = u1 + D_HID;               // 256
  float* v1 = u2 + D_LAT;               // 512
  float* v2 = v1 + KCAT;                // 1024
  float* Xh = v2 + D_HID;               // 7*SLOT
  float* Fh = Xh + NRING * SLOT;        // 7*SLOT
  __hip_bfloat16* W1b = (__hip_bfloat16*)(Fh + NRING * SLOT);  // 524288
  __hip_bfloat16* W2b = W1b + D_HID * KCAT;                    // 262144
  __hip_bfloat16* zc = W2b + D_LAT * D_HID;                    // 2048*512
  __hip_bfloat16* hb = zc + B_ROWS * KCAT;                     // 2048*1024
  // ~37.2 MB total

  // init: zc = [0 | bf16(ctx)], u = ones
  init_kernel<<<(B_ROWS * KCAT + 255) / 256, 256, 0, stream>>>(ctx, zc, u1, u2);

  // power iteration: 20 x (v = 0.5 W^T u; u = 0.5 W v), then v_raw = W^T u
  for (int it = 0; it < 20; it++) {
    s1_kernel<<<24, 256, 0, stream>>>(W1, W2, u1, u2, v1, v2, 0.5f);
    s2_kernel<<<(D_HID + D_LAT) / 4, 256, 0, stream>>>(W1, W2, v1, v2, u1, u2);
  }
  s1_kernel<<<24, 256, 0, stream>>>(W1, W2, u1, u2, v1, v2, 1.0f);
  sigma_kernel<<<1, 256, 0, stream>>>(u1, u2, v1, v2, sig);
  wfold_kernel<<<(D_HID * KCAT + D_LAT * D_HID + 255) / 256, 256, 0, stream>>>(
      W1, W2, sig, W1b, W2b);

  // x0 = 0 (f32 history slot 0); zc left half already bf16(0)
  hipMemsetAsync(Xh, 0, SLOT * sizeof(float), stream);

  // F0 = f(x0)
  eval_f(zc, W1b, W2b, b1, b2, hb, Fh, stream);
  // X1 = F0; z = bf16(F0); F1 = f(X1)
  hipMemcpyAsync(Xh + SLOT, Fh, SLOT * sizeof(float), hipMemcpyDeviceToDevice,
                 stream);
  zcast_kernel<<<SLOT / 256, 256, 0, stream>>>(Fh, zc);
  eval_f(zc, W1b, W2b, b1, b2, hb, Fh + SLOT, stream);
  // X2 = F0; F2 = F1 (reference's duplicated warm-up)
  hipMemcpyAsync(Xh + 2 * SLOT, Fh, SLOT * sizeof(float),
                 hipMemcpyDeviceToDevice, stream);
  hipMemcpyAsync(Fh + 2 * SLOT, Fh + SLOT, SLOT * sizeof(float),
                 hipMemcpyDeviceToDevice, stream);

  // Anderson loop: t = 3..25
  for (int t = 3; t <= 25; t++) {
    int mk = (t - 1 < 5) ? (t - 1) : 5;
    float* Xw = (t == 25) ? out : (Xh + (t % NRING) * SLOT);
    __hip_bfloat16* zarg = (t == 25) ? nullptr : zc;
    anderson_step_kernel<<<B_ROWS / 4, 256, 0, stream>>>(Xh, Fh, Xw, zarg, t, mk);
    if (t < 25) {
      eval_f(zc, W1b, W2b, b1, b2, hb, Fh + (t % NRING) * SLOT, stream);
    }
  }
}

// Round 4
// 1841.801 us; speedup vs baseline: 5.1629x; 1.3661x over previous
//
#include <hip/hip_runtime.h>
#include <hip/hip_bf16.h>

// ---------------------------------------------------------------------------
// DEQ layer, MI355X round 3.
//  - Spectral norm: Gram-operator power iteration. u_{k+1} = (W W^T) u_k with
//    G precomputed once (f32 tile GEMM, 272 blocks). 21 joint matvec launches
//    (wave/row, float4). sigma = sqrt(u20.u21)/||u20||; per-step l2norm in the
//    reference is scale-only and cancels (round-2 verified this folding).
//  - GEMMs: bf16 MFMA 16x16x32, global_load_lds w=16, XOR-octet swizzle,
//    sigma folded into bf16 weights pre-round, fused bias+tanh (round-2 code).
//  - Anderson: wave-per-row, f64 5x5 solve, 7-slot ring (round-1 verified).
// ---------------------------------------------------------------------------

#define B_ROWS 2048
#define D_LAT  256
#define D_CTX  256
#define D_HID  1024
#define KCAT   512
#define SLOT   (B_ROWS * D_LAT)
#define NRING  7

typedef __bf16 bf16x8 __attribute__((ext_vector_type(8)));
typedef float f32x4 __attribute__((ext_vector_type(4)));
typedef unsigned short u16;

// ---------------- init: zc = [bf16(0) | bf16(ctx)], u1=u2=1 ----------------
__global__ void init_kernel(const float* __restrict__ ctx,
                            __hip_bfloat16* __restrict__ zc,
                            float* __restrict__ u1, float* __restrict__ u2) {
  int i = blockIdx.x * 256 + threadIdx.x;
  if (i < B_ROWS * KCAT) {
    int b = i >> 9, c = i & 511;
    float v = (c < 256) ? 0.0f : ctx[b * 256 + (c - 256)];
    zc[i] = __float2bfloat16(v);
  }
  if (i < D_HID) u1[i] = 1.0f;
  if (i < D_LAT) u2[i] = 1.0f;
}

// ---------------- Gram: G = W W^T for both weights -------------------------
// blocks 0..255: G1 (16x16 tiles of 64), 256..271: G2 (4x4 tiles of 64).
__global__ __launch_bounds__(256) void gram_kernel(
    const float* __restrict__ W1, const float* __restrict__ W2,
    float* __restrict__ G1, float* __restrict__ G2) {
  const float* W; float* G; int C, R, ti, tj;
  int b = blockIdx.x;
  if (b < 256) { W = W1; G = G1; C = KCAT;  R = D_HID; ti = b >> 4; tj = b & 15; }
  else { b -= 256; W = W2; G = G2; C = D_HID; R = D_LAT; ti = b >> 2; tj = b & 3; }

  __shared__ float As[32][65];
  __shared__ float Bs[32][65];
  const int tid = threadIdx.x;
  const int tx = tid & 15, ty = tid >> 4;
  float acc[4][4] = {};

  for (int k0 = 0; k0 < C; k0 += 32) {
    for (int idx = tid; idx < 64 * 32; idx += 256) {
      int r = idx >> 5, c = idx & 31;
      As[c][r] = W[(size_t)(ti * 64 + r) * C + k0 + c];
      Bs[c][r] = W[(size_t)(tj * 64 + r) * C + k0 + c];
    }
    __syncthreads();
#pragma unroll
    for (int kk = 0; kk < 32; kk++) {
      float a[4], bb[4];
#pragma unroll
      for (int i = 0; i < 4; i++) a[i] = As[kk][ty * 4 + i];
#pragma unroll
      for (int j = 0; j < 4; j++) bb[j] = Bs[kk][tx * 4 + j];
#pragma unroll
      for (int i = 0; i < 4; i++)
#pragma unroll
        for (int j = 0; j < 4; j++) acc[i][j] += a[i] * bb[j];
    }
    __syncthreads();
  }
#pragma unroll
  for (int i = 0; i < 4; i++)
#pragma unroll
    for (int j = 0; j < 4; j++)
      G[(size_t)(ti * 64 + ty * 4 + i) * R + tj * 64 + tx * 4 + j] = acc[i][j];
}

// ---------------- joint power-iteration matvec: u_out = G u_in -------------
// 320 blocks x 4 waves: global waves 0..1023 -> G1 rows, 1024..1279 -> G2.
__global__ __launch_bounds__(256) void pmv_kernel(
    const float* __restrict__ G1, const float* __restrict__ G2,
    const float* __restrict__ u1i, const float* __restrict__ u2i,
    float* __restrict__ u1o, float* __restrict__ u2o) {
  int gw = blockIdx.x * 4 + (threadIdx.x >> 6);
  int lane = threadIdx.x & 63;
  const float* G; const float* ui; float* uo; int n, r;
  if (gw < D_HID) { G = G1; ui = u1i; uo = u1o; n = D_HID; r = gw; }
  else            { G = G2; ui = u2i; uo = u2o; n = D_LAT; r = gw - D_HID; }
  const float4* Gr = (const float4*)(G + (size_t)r * n);
  const float4* uv = (const float4*)ui;
  float acc = 0.f;
  for (int c = lane; c < (n >> 2); c += 64) {
    float4 g = Gr[c], u = uv[c];
    acc += g.x * u.x + g.y * u.y + g.z * u.z + g.w * u.w;
  }
  for (int off = 32; off; off >>= 1) acc += __shfl_down(acc, off, 64);
  if (lane == 0) uo[r] = acc;
}

// ---------------- sigma: 1/sig = sqrt((u20.u20)/(u20.u21)) -----------------
__global__ __launch_bounds__(256) void sigma_kernel(
    const float* __restrict__ u1A, const float* __restrict__ u1B,
    const float* __restrict__ u2A, const float* __restrict__ u2B,
    float* __restrict__ sig) {
  float s[4] = {0.f, 0.f, 0.f, 0.f};
  for (int i = threadIdx.x; i < D_HID; i += 256) {
    s[0] += u1A[i] * u1A[i];
    s[1] += u1A[i] * u1B[i];
  }
  for (int i = threadIdx.x; i < D_LAT; i += 256) {
    s[2] += u2A[i] * u2A[i];
    s[3] += u2A[i] * u2B[i];
  }
  __shared__ float red[4][4];
  int lane = threadIdx.x & 63, w = threadIdx.x >> 6;
  for (int k = 0; k < 4; k++) {
    float a = s[k];
    for (int off = 32; off; off >>= 1) a += __shfl_down(a, off, 64);
    if (lane == 0) red[k][w] = a;
  }
  __syncthreads();
  if (threadIdx.x == 0) {
    float d11 = red[0][0] + red[0][1] + red[0][2] + red[0][3];
    float d12 = red[1][0] + red[1][1] + red[1][2] + red[1][3];
    float d21 = red[2][0] + red[2][1] + red[2][2] + red[2][3];
    float d22 = red[3][0] + red[3][1] + red[3][2] + red[3][3];
    sig[0] = sqrtf(d11 / d12);   // = ||u20|| / ||W1^T u20|| = 1/sigma1
    sig[1] = sqrtf(d21 / d22);
  }
}

// ---------------- fold sigma into bf16 weights -----------------------------
__global__ void wfold_kernel(const float* __restrict__ W1,
                             const float* __restrict__ W2,
                             const float* __restrict__ sig,
                             __hip_bfloat16* __restrict__ W1b,
                             __hip_bfloat16* __restrict__ W2b) {
  int i = blockIdx.x * 256 + threadIdx.x;
  if (i < D_HID * KCAT) W1b[i] = __float2bfloat16(W1[i] * sig[0]);
  int j = i - D_HID * KCAT;
  if (j >= 0 && j < D_LAT * D_HID) W2b[j] = __float2bfloat16(W2[j] * sig[1]);
}

// ---------------- cast F0 into zc left half --------------------------------
__global__ void zcast_kernel(const float* __restrict__ z,
                             __hip_bfloat16* __restrict__ zc) {
  int i = blockIdx.x * 256 + threadIdx.x;   // over 2048*256
  int b = i >> 8, c = i & 255;
  zc[b * KCAT + c] = __float2bfloat16(z[i]);
}

// ---------------- bf16 MFMA GEMM: C = tanh(A @ W^T + bias) -----------------
template <int BM, int BN, bool OUT_BF16>
__global__ __launch_bounds__(256) void gemm_mfma(
    const __hip_bfloat16* __restrict__ A, const __hip_bfloat16* __restrict__ W,
    int K, const float* __restrict__ bias, float* __restrict__ Cf,
    __hip_bfloat16* __restrict__ Cb, int N) {
  __shared__ __align__(16) u16 lds[(BM + BN) * 64];
  u16* As = lds;
  u16* Ws = lds + BM * 64;
  const int tid = threadIdx.x;
  const int lane = tid & 63;
  const int wid = tid >> 6;
  const int wy = wid >> 1, wx = wid & 1;
  constexpr int WM = BM / 2, WN = BN / 2;
  constexpr int MB = WM / 16, NB = WN / 16;
  const int bm = blockIdx.x * BM;
  const int bn = blockIdx.y * BN;
  const int rlo = lane & 15, quad = lane >> 4;

  f32x4 acc[MB][NB] = {};

  for (int k0 = 0; k0 < K; k0 += 64) {
    for (int c = tid; c < BM * 8; c += 256) {
      int r = c >> 3, o = (c & 7) ^ (r & 7);
      __builtin_amdgcn_global_load_lds(
          (const __attribute__((address_space(1))) void*)(A + (size_t)(bm + r) * K + k0 + o * 8),
          (__attribute__((address_space(3))) void*)(As + c * 8), 16, 0, 0);
    }
    for (int c = tid; c < BN * 8; c += 256) {
      int r = c >> 3, o = (c & 7) ^ (r & 7);
      __builtin_amdgcn_global_load_lds(
          (const __attribute__((address_space(1))) void*)(W + (size_t)(bn + r) * K + k0 + o * 8),
          (__attribute__((address_space(3))) void*)(Ws + c * 8), 16, 0, 0);
    }
    __syncthreads();
#pragma unroll
    for (int kk = 0; kk < 2; kk++) {
      bf16x8 af[MB], bfr[NB];
#pragma unroll
      for (int mb = 0; mb < MB; mb++) {
        int r = wy * WM + mb * 16 + rlo;
        int o = (kk * 4 + quad) ^ (r & 7);
        af[mb] = *(const bf16x8*)(As + (r * 8 + o) * 8);
      }
#pragma unroll
      for (int nb = 0; nb < NB; nb++) {
        int r = wx * WN + nb * 16 + rlo;
        int o = (kk * 4 + quad) ^ (r & 7);
        bfr[nb] = *(const bf16x8*)(Ws + (r * 8 + o) * 8);
      }
#pragma unroll
      for (int mb = 0; mb < MB; mb++)
#pragma unroll
        for (int nb = 0; nb < NB; nb++)
          acc[mb][nb] = __builtin_amdgcn_mfma_f32_16x16x32_bf16(
              af[mb], bfr[nb], acc[mb][nb], 0, 0, 0);
    }
    __syncthreads();
  }

#pragma unroll
  for (int mb = 0; mb < MB; mb++) {
#pragma unroll
    for (int nb = 0; nb < NB; nb++) {
      int n = bn + wx * WN + nb * 16 + rlo;
      float bv = bias[n];
#pragma unroll
      for (int rg = 0; rg < 4; rg++) {
        int m = bm + wy * WM + mb * 16 + quad * 4 + rg;
        float val = tanhf(acc[mb][nb][rg] + bv);
        if constexpr (OUT_BF16) {
          Cb[(size_t)m * N + n] = __float2bfloat16(val);
        } else {
          Cf[(size_t)m * N + n] = val;
        }
      }
    }
  }
}

// ---------------- Anderson step (wave per batch row) ------------------------
__global__ __launch_bounds__(256) void anderson_step_kernel(
    const float* __restrict__ Xh, const float* __restrict__ Fh,
    float* __restrict__ Xw, __hip_bfloat16* __restrict__ zc, int t, int mk) {
  const int lane = threadIdx.x & 63;
  const int wid = threadIdx.x >> 6;
  const int b = blockIdx.x * 4 + wid;
  const int base = b * D_LAT + lane;

  float fa[4], xa[4], r[4], Fm1[4];
#pragma unroll
  for (int c = 0; c < 4; c++) {
    int sl = (t - 1) % NRING;
    fa[c] = Fh[sl * SLOT + base + 64 * c];
    xa[c] = Xh[sl * SLOT + base + 64 * c];
    r[c] = fa[c] - xa[c];
    Fm1[c] = fa[c];
  }

  float dF[5][4], dG[5][4];
  for (int i = 1; i <= mk; i++) {
    int sl = (t - 1 - i) % NRING;
#pragma unroll
    for (int c = 0; c < 4; c++) {
      float fb = Fh[sl * SLOT + base + 64 * c];
      float xb = Xh[sl * SLOT + base + 64 * c];
      dF[i - 1][c] = fa[c] - fb;
      float dx = xa[c] - xb;
      dG[i - 1][c] = dF[i - 1][c] - dx;
      fa[c] = fb;
      xa[c] = xb;
    }
  }

  float vals[20];
  int nv = 0;
  for (int i = 0; i < mk; i++)
    for (int j = i; j < mk; j++) {
      float s = 0.f;
#pragma unroll
      for (int c = 0; c < 4; c++) s += dG[i][c] * dG[j][c];
      vals[nv++] = s;
    }
  for (int i = 0; i < mk; i++) {
    float s = 0.f;
#pragma unroll
    for (int c = 0; c < 4; c++) s += dG[i][c] * r[c];
    vals[nv++] = s;
  }
  for (int off = 1; off <= 32; off <<= 1)
    for (int v = 0; v < nv; v++) vals[v] += __shfl_xor(vals[v], off, 64);

  double A[5][5], bv[5], alpha[5];
  int p = 0;
  for (int i = 0; i < mk; i++)
    for (int j = i; j < mk; j++) {
      A[i][j] = (double)vals[p];
      A[j][i] = (double)vals[p];
      p++;
    }
  for (int i = 0; i < mk; i++) A[i][i] += (double)1e-4f;
  for (int i = 0; i < mk; i++) bv[i] = (double)vals[p++];

  for (int c = 0; c < mk; c++) {
    double inv = 1.0 / A[c][c];
    for (int rr = c + 1; rr < mk; rr++) {
      double fct = A[rr][c] * inv;
      for (int cc = c; cc < mk; cc++) A[rr][cc] -= fct * A[c][cc];
      bv[rr] -= fct * bv[c];
    }
  }
  for (int i = mk - 1; i >= 0; i--) {
    double s = bv[i];
    for (int j = i + 1; j < mk; j++) s -= A[i][j] * alpha[j];
    alpha[i] = s / A[i][i];
  }

#pragma unroll
  for (int c = 0; c < 4; c++) {
    float x = Fm1[c];
    for (int i = 0; i < mk; i++) x -= dF[i][c] * (float)alpha[i];
    Xw[base + 64 * c] = x;
    if (zc != nullptr) zc[b * KCAT + lane + 64 * c] = __float2bfloat16(x);
  }
}

// ---------------- host orchestration ---------------------------------------
static void eval_f(const __hip_bfloat16* zc, const __hip_bfloat16* W1b,
                   const __hip_bfloat16* W2b, const float* b1, const float* b2,
                   __hip_bfloat16* hb, float* Fout, hipStream_t stream) {
  gemm_mfma<64, 128, true><<<dim3(B_ROWS / 64, D_HID / 128), 256, 0, stream>>>(
      zc, W1b, KCAT, b1, nullptr, hb, D_HID);
  gemm_mfma<64, 64, false><<<dim3(B_ROWS / 64, D_LAT / 64), 256, 0, stream>>>(
      hb, W2b, D_HID, b2, Fout, nullptr, D_LAT);
}

extern "C" void kernel_launch(void* const* d_in, const int* in_sizes, int n_in,
                              void* d_out, int out_size, void* d_ws,
                              size_t ws_size, hipStream_t stream) {
  const float* ctx = (const float*)d_in[0];
  const float* W1 = (const float*)d_in[1];
  const float* b1 = (const float*)d_in[2];
  const float* W2 = (const float*)d_in[3];
  const float* b2 = (const float*)d_in[4];
  float* out = (float*)d_out;

  float* ws = (float*)d_ws;
  float* sig = ws;                      // 16
  float* u1A = ws + 16;                 // 1024
  float* u1B = u1A + D_HID;             // 1024
  float* u2A = u1B + D_HID;             // 256
  float* u2B = u2A + D_LAT;             // 256
  float* G1 = u2B + D_LAT;              // 1024*1024
  float* G2 = G1 + D_HID * D_HID;       // 256*256
  float* Xh = G2 + D_LAT * D_LAT;       // 7*SLOT
  float* Fh = Xh + NRING * SLOT;        // 7*SLOT
  __hip_bfloat16* W1b = (__hip_bfloat16*)(Fh + NRING * SLOT);  // 524288
  __hip_bfloat16* W2b = W1b + D_HID * KCAT;                    // 262144
  __hip_bfloat16* zc = W2b + D_LAT * D_HID;                    // 2048*512
  __hip_bfloat16* hb = zc + B_ROWS * KCAT;                     // 2048*1024
  // ~41.7 MB total

  // init: zc = [0 | bf16(ctx)], u = ones
  init_kernel<<<(B_ROWS * KCAT + 255) / 256, 256, 0, stream>>>(ctx, zc, u1A, u2A);

  // Gram matrices, then 21 power-iteration matvecs (u20 ends in A, u21 in B).
  gram_kernel<<<272, 256, 0, stream>>>(W1, W2, G1, G2);
  for (int it = 0; it < 21; it++) {
    const float* i1 = (it & 1) ? u1B : u1A;
    const float* i2 = (it & 1) ? u2B : u2A;
    float* o1 = (it & 1) ? u1A : u1B;
    float* o2 = (it & 1) ? u2A : u2B;
    pmv_kernel<<<320, 256, 0, stream>>>(G1, G2, i1, i2, o1, o2);
  }
  sigma_kernel<<<1, 256, 0, stream>>>(u1A, u1B, u2A, u2B, sig);
  wfold_kernel<<<(D_HID * KCAT + D_LAT * D_HID + 255) / 256, 256, 0, stream>>>(
      W1, W2, sig, W1b, W2b);

  // x0 = 0 (f32 history slot 0); zc left half already bf16(0)
  hipMemsetAsync(Xh, 0, SLOT * sizeof(float), stream);

  // F0 = f(x0)
  eval_f(zc, W1b, W2b, b1, b2, hb, Fh, stream);
  // X1 = F0; z = bf16(F0); F1 = f(X1)
  hipMemcpyAsync(Xh + SLOT, Fh, SLOT * sizeof(float), hipMemcpyDeviceToDevice,
                 stream);
  zcast_kernel<<<SLOT / 256, 256, 0, stream>>>(Fh, zc);
  eval_f(zc, W1b, W2b, b1, b2, hb, Fh + SLOT, stream);
  // X2 = F0; F2 = F1 (reference's duplicated warm-up)
  hipMemcpyAsync(Xh + 2 * SLOT, Fh, SLOT * sizeof(float),
                 hipMemcpyDeviceToDevice, stream);
  hipMemcpyAsync(Fh + 2 * SLOT, Fh + SLOT, SLOT * sizeof(float),
                 hipMemcpyDeviceToDevice, stream);

  // Anderson loop: t = 3..25
  for (int t = 3; t <= 25; t++) {
    int mk = (t - 1 < 5) ? (t - 1) : 5;
    float* Xw = (t == 25) ? out : (Xh + (t % NRING) * SLOT);
    __hip_bfloat16* zarg = (t == 25) ? nullptr : zc;
    anderson_step_kernel<<<B_ROWS / 4, 256, 0, stream>>>(Xh, Fh, Xw, zarg, t, mk);
    if (t < 25) {
      eval_f(zc, W1b, W2b, b1, b2, hb, Fh + (t % NRING) * SLOT, stream);
    }
  }
}

// Round 5
// 1744.131 us; speedup vs baseline: 5.4520x; 1.0560x over previous
//
#include <hip/hip_runtime.h>
#include <hip/hip_bf16.h>

// ---------------------------------------------------------------------------
// DEQ layer, MI355X round 4.
//  - Spectral: small-side Gram iteration. G1' = W1^T W1 (512^2), G2 = W2 W2^T
//    (256^2), built by one split-K x8 f32 kernel (pad-66 LDS, float2 reads,
//    atomicAdd). v-chain: v1 = W1^T ones (colsum), v_{k+1} = 0.25*G1' v_k;
//    u-chain: u_{k+1} = 0.25*G2 u_k. Exact identities give sigma with the
//    0.25 damping compensated exactly (power of 2).
//  - GEMMs: bf16 MFMA 16x16x32 (verified rounds 2-4). Anderson: verified.
//  - Warm-up memcpys fused into warm1/warm2 kernels.
// ---------------------------------------------------------------------------

#define B_ROWS 2048
#define D_LAT  256
#define D_CTX  256
#define D_HID  1024
#define KCAT   512
#define SLOT   (B_ROWS * D_LAT)
#define NRING  7

typedef __bf16 bf16x8 __attribute__((ext_vector_type(8)));
typedef float f32x4 __attribute__((ext_vector_type(4)));
typedef unsigned short u16;

// ---------------- init: zc = [bf16(0)|bf16(ctx)], uA=1, vA=0, G=0 ----------
__global__ void init_kernel(const float* __restrict__ ctx,
                            __hip_bfloat16* __restrict__ zc,
                            float* __restrict__ vA, float* __restrict__ uA,
                            float* __restrict__ G1p, float* __restrict__ G2) {
  int i = blockIdx.x * 256 + threadIdx.x;
  if (i < B_ROWS * KCAT) {
    int b = i >> 9, c = i & 511;
    float v = (c < 256) ? 0.0f : ctx[b * 256 + (c - 256)];
    zc[i] = __float2bfloat16(v);
  }
  if (i < 512 * 512) G1p[i] = 0.0f;
  if (i < 256 * 256) G2[i] = 0.0f;
  if (i < KCAT) vA[i] = 0.0f;
  if (i < D_LAT) uA[i] = 1.0f;
}

// ---------------- Gram build, split-K x8, atomic accumulate ----------------
// blocks 0..511:  G1' = W1^T W1  (mode A: G[i][j] = sum_k X[k*512+i]X[k*512+j])
//   tiles 8x8 of 64, splits of K=128 over W1's 1024 rows.
// blocks 512..639: G2 = W2 W2^T (mode B: G[i][j] = sum_k X[i*1024+k]X[j*1024+k])
//   tiles 4x4 of 64, splits of 128 over W2's 1024 cols.
__global__ __launch_bounds__(256) void gram_kernel(
    const float* __restrict__ W1, const float* __restrict__ W2,
    float* __restrict__ G1p, float* __restrict__ G2) {
  __shared__ float As[32][66];
  __shared__ float Bs[32][66];
  const int tid = threadIdx.x;
  const int tx = tid & 15, ty = tid >> 4;

  const float* X; float* G; int N, ti, tj, k0base; bool modeA;
  int b = blockIdx.x;
  if (b < 512) {
    modeA = true; X = W1; G = G1p; N = 512;
    int s = b >> 6, t = b & 63;
    ti = t >> 3; tj = t & 7; k0base = s * 128;
  } else {
    modeA = false; b -= 512; X = W2; G = G2; N = 256;
    int s = b >> 4, t = b & 15;
    ti = t >> 2; tj = t & 3; k0base = s * 128;
  }

  float acc[4][4] = {};
  for (int k0 = k0base; k0 < k0base + 128; k0 += 32) {
    if (modeA) {
      for (int idx = tid; idx < 2048; idx += 256) {
        int r = idx & 63, c = idx >> 6;
        As[c][r] = X[(size_t)(k0 + c) * 512 + ti * 64 + r];
        Bs[c][r] = X[(size_t)(k0 + c) * 512 + tj * 64 + r];
      }
    } else {
      for (int idx = tid; idx < 2048; idx += 256) {
        int c = idx & 31, r = idx >> 5;
        As[c][r] = X[(size_t)(ti * 64 + r) * 1024 + k0 + c];
        Bs[c][r] = X[(size_t)(tj * 64 + r) * 1024 + k0 + c];
      }
    }
    __syncthreads();
#pragma unroll
    for (int kk = 0; kk < 32; kk++) {
      const float2* ap = (const float2*)&As[kk][ty * 4];
      const float2* bp = (const float2*)&Bs[kk][tx * 4];
      float2 a0 = ap[0], a1 = ap[1];
      float2 b0 = bp[0], b1 = bp[1];
      float a[4] = {a0.x, a0.y, a1.x, a1.y};
      float bb[4] = {b0.x, b0.y, b1.x, b1.y};
#pragma unroll
      for (int i = 0; i < 4; i++)
#pragma unroll
        for (int j = 0; j < 4; j++) acc[i][j] += a[i] * bb[j];
    }
    __syncthreads();
  }
#pragma unroll
  for (int i = 0; i < 4; i++)
#pragma unroll
    for (int j = 0; j < 4; j++)
      atomicAdd(&G[(size_t)(ti * 64 + ty * 4 + i) * N + tj * 64 + tx * 4 + j],
                acc[i][j]);
}

// ---------------- colsum: vA += W1^T ones (atomic partials) ----------------
__global__ __launch_bounds__(256) void colsum_kernel(
    const float* __restrict__ W1, float* __restrict__ vA) {
  int b = blockIdx.x;  // 64 blocks, rows [16b,16b+16)
  for (int c = threadIdx.x; c < KCAT; c += 256) {
    float s = 0.f;
#pragma unroll
    for (int r = 0; r < 16; r++) s += W1[(size_t)(16 * b + r) * KCAT + c];
    atomicAdd(&vA[c], s);
  }
}

// ---------------- joint power matvec: out = 0.25 * G in --------------------
// 192 blocks x 4 waves: gw 0..511 -> G1' rows (only if g1_active), 512..767 -> G2.
__global__ __launch_bounds__(256) void pmv_kernel(
    const float* __restrict__ G1p, const float* __restrict__ G2,
    const float* __restrict__ vi, float* __restrict__ vo,
    const float* __restrict__ ui, float* __restrict__ uo, int g1_active) {
  int gw = blockIdx.x * 4 + (threadIdx.x >> 6);
  int lane = threadIdx.x & 63;
  const float* G; const float* in; float* out; int n, r;
  if (gw < 512) {
    if (!g1_active) return;
    G = G1p; in = vi; out = vo; n = 512; r = gw;
  } else {
    G = G2; in = ui; out = uo; n = 256; r = gw - 512;
  }
  const float4* Gr = (const float4*)(G + (size_t)r * n);
  const float4* uv = (const float4*)in;
  float acc = 0.f;
  for (int c = lane; c < (n >> 2); c += 64) {
    float4 g = Gr[c], u = uv[c];
    acc += g.x * u.x + g.y * u.y + g.z * u.z + g.w * u.w;
  }
  for (int off = 32; off; off >>= 1) acc += __shfl_down(acc, off, 64);
  if (lane == 0) out[r] = 0.25f * acc;
}

// ---------------- sigma ----------------------------------------------------
// vA=v^21, vB=v^20 (damped), uA=u^20, uB=u^21 (damped). s=0.25 compensated:
// 1/sig1 = sqrt(s * (vB.vA)/(vA.vA)); 1/sig2 = sqrt(s * (uA.uA)/(uA.uB)).
__global__ __launch_bounds__(256) void sigma_kernel(
    const float* __restrict__ vA, const float* __restrict__ vB,
    const float* __restrict__ uA, const float* __restrict__ uB,
    float* __restrict__ sig) {
  float s[4] = {0.f, 0.f, 0.f, 0.f};
  for (int i = threadIdx.x; i < KCAT; i += 256) {
    s[0] += vA[i] * vB[i];
    s[1] += vA[i] * vA[i];
  }
  for (int i = threadIdx.x; i < D_LAT; i += 256) {
    s[2] += uA[i] * uA[i];
    s[3] += uA[i] * uB[i];
  }
  __shared__ float red[4][4];
  int lane = threadIdx.x & 63, w = threadIdx.x >> 6;
  for (int k = 0; k < 4; k++) {
    float a = s[k];
    for (int off = 32; off; off >>= 1) a += __shfl_down(a, off, 64);
    if (lane == 0) red[k][w] = a;
  }
  __syncthreads();
  if (threadIdx.x == 0) {
    float d0 = red[0][0] + red[0][1] + red[0][2] + red[0][3];
    float d1 = red[1][0] + red[1][1] + red[1][2] + red[1][3];
    float d2 = red[2][0] + red[2][1] + red[2][2] + red[2][3];
    float d3 = red[3][0] + red[3][1] + red[3][2] + red[3][3];
    sig[0] = sqrtf(0.25f * d0 / d1);
    sig[1] = sqrtf(0.25f * d2 / d3);
  }
}

// ---------------- fold sigma into bf16 weights -----------------------------
__global__ void wfold_kernel(const float* __restrict__ W1,
                             const float* __restrict__ W2,
                             const float* __restrict__ sig,
                             __hip_bfloat16* __restrict__ W1b,
                             __hip_bfloat16* __restrict__ W2b) {
  int i = blockIdx.x * 256 + threadIdx.x;
  if (i < D_HID * KCAT) W1b[i] = __float2bfloat16(W1[i] * sig[0]);
  int j = i - D_HID * KCAT;
  if (j >= 0 && j < D_LAT * D_HID) W2b[j] = __float2bfloat16(W2[j] * sig[1]);
}

// ---------------- warm-up fusions ------------------------------------------
// warm1: X1 = F0; zc left = bf16(F0)
__global__ void warm1_kernel(const float* __restrict__ Fh,
                             float* __restrict__ Xh,
                             __hip_bfloat16* __restrict__ zc) {
  int i = blockIdx.x * 256 + threadIdx.x;
  float v = Fh[i];
  Xh[SLOT + i] = v;
  zc[(i >> 8) * KCAT + (i & 255)] = __float2bfloat16(v);
}
// warm2: X2 = F0; F2 = F1
__global__ void warm2_kernel(const float* __restrict__ Fh,
                             float* __restrict__ Xh, float* __restrict__ Fw) {
  int i = blockIdx.x * 256 + threadIdx.x;
  Xh[2 * SLOT + i] = Fh[i];
  Fw[2 * SLOT + i] = Fh[SLOT + i];
}

// ---------------- bf16 MFMA GEMM: C = tanh(A @ W^T + bias) -----------------
template <int BM, int BN, bool OUT_BF16>
__global__ __launch_bounds__(256) void gemm_mfma(
    const __hip_bfloat16* __restrict__ A, const __hip_bfloat16* __restrict__ W,
    int K, const float* __restrict__ bias, float* __restrict__ Cf,
    __hip_bfloat16* __restrict__ Cb, int N) {
  __shared__ __align__(16) u16 lds[(BM + BN) * 64];
  u16* As = lds;
  u16* Ws = lds + BM * 64;
  const int tid = threadIdx.x;
  const int lane = tid & 63;
  const int wid = tid >> 6;
  const int wy = wid >> 1, wx = wid & 1;
  constexpr int WM = BM / 2, WN = BN / 2;
  constexpr int MB = WM / 16, NB = WN / 16;
  const int bm = blockIdx.x * BM;
  const int bn = blockIdx.y * BN;
  const int rlo = lane & 15, quad = lane >> 4;

  f32x4 acc[MB][NB] = {};

  for (int k0 = 0; k0 < K; k0 += 64) {
    for (int c = tid; c < BM * 8; c += 256) {
      int r = c >> 3, o = (c & 7) ^ (r & 7);
      __builtin_amdgcn_global_load_lds(
          (const __attribute__((address_space(1))) void*)(A + (size_t)(bm + r) * K + k0 + o * 8),
          (__attribute__((address_space(3))) void*)(As + c * 8), 16, 0, 0);
    }
    for (int c = tid; c < BN * 8; c += 256) {
      int r = c >> 3, o = (c & 7) ^ (r & 7);
      __builtin_amdgcn_global_load_lds(
          (const __attribute__((address_space(1))) void*)(W + (size_t)(bn + r) * K + k0 + o * 8),
          (__attribute__((address_space(3))) void*)(Ws + c * 8), 16, 0, 0);
    }
    __syncthreads();
#pragma unroll
    for (int kk = 0; kk < 2; kk++) {
      bf16x8 af[MB], bfr[NB];
#pragma unroll
      for (int mb = 0; mb < MB; mb++) {
        int r = wy * WM + mb * 16 + rlo;
        int o = (kk * 4 + quad) ^ (r & 7);
        af[mb] = *(const bf16x8*)(As + (r * 8 + o) * 8);
      }
#pragma unroll
      for (int nb = 0; nb < NB; nb++) {
        int r = wx * WN + nb * 16 + rlo;
        int o = (kk * 4 + quad) ^ (r & 7);
        bfr[nb] = *(const bf16x8*)(Ws + (r * 8 + o) * 8);
      }
#pragma unroll
      for (int mb = 0; mb < MB; mb++)
#pragma unroll
        for (int nb = 0; nb < NB; nb++)
          acc[mb][nb] = __builtin_amdgcn_mfma_f32_16x16x32_bf16(
              af[mb], bfr[nb], acc[mb][nb], 0, 0, 0);
    }
    __syncthreads();
  }

#pragma unroll
  for (int mb = 0; mb < MB; mb++) {
#pragma unroll
    for (int nb = 0; nb < NB; nb++) {
      int n = bn + wx * WN + nb * 16 + rlo;
      float bv = bias[n];
#pragma unroll
      for (int rg = 0; rg < 4; rg++) {
        int m = bm + wy * WM + mb * 16 + quad * 4 + rg;
        float val = tanhf(acc[mb][nb][rg] + bv);
        if constexpr (OUT_BF16) {
          Cb[(size_t)m * N + n] = __float2bfloat16(val);
        } else {
          Cf[(size_t)m * N + n] = val;
        }
      }
    }
  }
}

// ---------------- Anderson step (wave per batch row) ------------------------
__global__ __launch_bounds__(256) void anderson_step_kernel(
    const float* __restrict__ Xh, const float* __restrict__ Fh,
    float* __restrict__ Xw, __hip_bfloat16* __restrict__ zc, int t, int mk) {
  const int lane = threadIdx.x & 63;
  const int wid = threadIdx.x >> 6;
  const int b = blockIdx.x * 4 + wid;
  const int base = b * D_LAT + lane;

  float fa[4], xa[4], r[4], Fm1[4];
#pragma unroll
  for (int c = 0; c < 4; c++) {
    int sl = (t - 1) % NRING;
    fa[c] = Fh[sl * SLOT + base + 64 * c];
    xa[c] = Xh[sl * SLOT + base + 64 * c];
    r[c] = fa[c] - xa[c];
    Fm1[c] = fa[c];
  }

  float dF[5][4], dG[5][4];
  for (int i = 1; i <= mk; i++) {
    int sl = (t - 1 - i) % NRING;
#pragma unroll
    for (int c = 0; c < 4; c++) {
      float fb = Fh[sl * SLOT + base + 64 * c];
      float xb = Xh[sl * SLOT + base + 64 * c];
      dF[i - 1][c] = fa[c] - fb;
      float dx = xa[c] - xb;
      dG[i - 1][c] = dF[i - 1][c] - dx;
      fa[c] = fb;
      xa[c] = xb;
    }
  }

  float vals[20];
  int nv = 0;
  for (int i = 0; i < mk; i++)
    for (int j = i; j < mk; j++) {
      float s = 0.f;
#pragma unroll
      for (int c = 0; c < 4; c++) s += dG[i][c] * dG[j][c];
      vals[nv++] = s;
    }
  for (int i = 0; i < mk; i++) {
    float s = 0.f;
#pragma unroll
    for (int c = 0; c < 4; c++) s += dG[i][c] * r[c];
    vals[nv++] = s;
  }
  for (int off = 1; off <= 32; off <<= 1)
    for (int v = 0; v < nv; v++) vals[v] += __shfl_xor(vals[v], off, 64);

  double A[5][5], bv[5], alpha[5];
  int p = 0;
  for (int i = 0; i < mk; i++)
    for (int j = i; j < mk; j++) {
      A[i][j] = (double)vals[p];
      A[j][i] = (double)vals[p];
      p++;
    }
  for (int i = 0; i < mk; i++) A[i][i] += (double)1e-4f;
  for (int i = 0; i < mk; i++) bv[i] = (double)vals[p++];

  for (int c = 0; c < mk; c++) {
    double inv = 1.0 / A[c][c];
    for (int rr = c + 1; rr < mk; rr++) {
      double fct = A[rr][c] * inv;
      for (int cc = c; cc < mk; cc++) A[rr][cc] -= fct * A[c][cc];
      bv[rr] -= fct * bv[c];
    }
  }
  for (int i = mk - 1; i >= 0; i--) {
    double s = bv[i];
    for (int j = i + 1; j < mk; j++) s -= A[i][j] * alpha[j];
    alpha[i] = s / A[i][i];
  }

#pragma unroll
  for (int c = 0; c < 4; c++) {
    float x = Fm1[c];
    for (int i = 0; i < mk; i++) x -= dF[i][c] * (float)alpha[i];
    Xw[base + 64 * c] = x;
    if (zc != nullptr) zc[b * KCAT + lane + 64 * c] = __float2bfloat16(x);
  }
}

// ---------------- host orchestration ---------------------------------------
static void eval_f(const __hip_bfloat16* zc, const __hip_bfloat16* W1b,
                   const __hip_bfloat16* W2b, const float* b1, const float* b2,
                   __hip_bfloat16* hb, float* Fout, hipStream_t stream) {
  gemm_mfma<64, 128, true><<<dim3(B_ROWS / 64, D_HID / 128), 256, 0, stream>>>(
      zc, W1b, KCAT, b1, nullptr, hb, D_HID);
  gemm_mfma<64, 64, false><<<dim3(B_ROWS / 64, D_LAT / 64), 256, 0, stream>>>(
      hb, W2b, D_HID, b2, Fout, nullptr, D_LAT);
}

extern "C" void kernel_launch(void* const* d_in, const int* in_sizes, int n_in,
                              void* d_out, int out_size, void* d_ws,
                              size_t ws_size, hipStream_t stream) {
  const float* ctx = (const float*)d_in[0];
  const float* W1 = (const float*)d_in[1];
  const float* b1 = (const float*)d_in[2];
  const float* W2 = (const float*)d_in[3];
  const float* b2 = (const float*)d_in[4];
  float* out = (float*)d_out;

  float* ws = (float*)d_ws;
  float* sig = ws;                       // 16
  float* vA = ws + 16;                   // 512
  float* vB = vA + KCAT;                 // 512
  float* uA = vB + KCAT;                 // 256
  float* uB = uA + D_LAT;                // 256
  float* G1p = uB + D_LAT;               // 512*512
  float* G2 = G1p + KCAT * KCAT;         // 256*256
  float* Xh = G2 + D_LAT * D_LAT;        // 7*SLOT
  float* Fh = Xh + NRING * SLOT;         // 7*SLOT
  __hip_bfloat16* W1b = (__hip_bfloat16*)(Fh + NRING * SLOT);  // 524288
  __hip_bfloat16* W2b = W1b + D_HID * KCAT;                    // 262144
  __hip_bfloat16* zc = W2b + D_LAT * D_HID;                    // 2048*512
  __hip_bfloat16* hb = zc + B_ROWS * KCAT;                     // 2048*1024
  // ~38.5 MB total

  // init: zc = [0|bf16(ctx)], uA = ones, vA = 0, G zeroed (atomic targets)
  init_kernel<<<(B_ROWS * KCAT + 255) / 256, 256, 0, stream>>>(ctx, zc, vA, uA,
                                                               G1p, G2);
  // Gram build + v1 = W1^T ones
  gram_kernel<<<640, 256, 0, stream>>>(W1, W2, G1p, G2);
  colsum_kernel<<<64, 256, 0, stream>>>(W1, vA);

  // joint damped power chain:
  //   u-side all 21 its (u0=ones -> u21); v-side its 2..21 (v1 -> v21)
  for (int it = 1; it <= 21; it++) {
    const float* vi; float* vo;
    const float* ui; float* uo;
    if (it & 1) { vi = vB; vo = vA; ui = uA; uo = uB; }
    else        { vi = vA; vo = vB; ui = uB; uo = uA; }
    pmv_kernel<<<192, 256, 0, stream>>>(G1p, G2, vi, vo, ui, uo, it >= 2);
  }
  // final: vA=v21, vB=v20, uA=u20, uB=u21
  sigma_kernel<<<1, 256, 0, stream>>>(vA, vB, uA, uB, sig);
  wfold_kernel<<<(D_HID * KCAT + D_LAT * D_HID + 255) / 256, 256, 0, stream>>>(
      W1, W2, sig, W1b, W2b);

  // x0 = 0 (f32 history slot 0); zc left half already bf16(0)
  hipMemsetAsync(Xh, 0, SLOT * sizeof(float), stream);

  // F0 = f(x0)
  eval_f(zc, W1b, W2b, b1, b2, hb, Fh, stream);
  // X1 = F0; zc = bf16(F0); F1 = f(X1)
  warm1_kernel<<<SLOT / 256, 256, 0, stream>>>(Fh, Xh, zc);
  eval_f(zc, W1b, W2b, b1, b2, hb, Fh + SLOT, stream);
  // X2 = F0; F2 = F1
  warm2_kernel<<<SLOT / 256, 256, 0, stream>>>(Fh, Xh, Fh);

  // Anderson loop: t = 3..25
  for (int t = 3; t <= 25; t++) {
    int mk = (t - 1 < 5) ? (t - 1) : 5;
    float* Xw = (t == 25) ? out : (Xh + (t % NRING) * SLOT);
    __hip_bfloat16* zarg = (t == 25) ? nullptr : zc;
    anderson_step_kernel<<<B_ROWS / 4, 256, 0, stream>>>(Xh, Fh, Xw, zarg, t, mk);
    if (t < 25) {
      eval_f(zc, W1b, W2b, b1, b2, hb, Fh + (t % NRING) * SLOT, stream);
    }
  }
}